// Round 10
// baseline (564.828 us; speedup 1.0000x reference)
//
#include <hip/hip_runtime.h>

typedef unsigned int uint;
typedef unsigned short ushort;

#define HID 128
#define NGRAPH 64

typedef __attribute__((ext_vector_type(8))) short short8;
typedef __attribute__((ext_vector_type(4))) float floatx4;

__device__ __forceinline__ float bflo(uint w){ return __uint_as_float(w<<16); }
__device__ __forceinline__ float bfhi(uint w){ return __uint_as_float(w & 0xffff0000u); }
__device__ __forceinline__ float bf2f(ushort u){ return __uint_as_float(((uint)u)<<16); }
__device__ __forceinline__ ushort f2bf(float f){
  uint u = __float_as_uint(f);
  u = u + 0x7fffu + ((u>>16)&1u);
  return (ushort)(u>>16);
}
__device__ __forceinline__ uint pack2(float a, float b){
  return (uint)f2bf(a) | ((uint)f2bf(b)<<16);
}
__device__ __forceinline__ float nanz(float v){ return (v==v) ? v : 0.f; }

__device__ __forceinline__ int bat(const int* b, int i, int is64){
  return is64 ? b[2*(size_t)i] : b[i];
}

// ---------------- prep: zero + detect + W repack, one dispatch ----------------
// blocks 0..511 : zero cnt/stats/pooled/xw-zero-row/bcnt; block 0 writes flags[1]
// blocks 512..519: repack W1/W2 into bf16 MFMA-B-fragment layout
__global__ void k_prep(int* __restrict__ cnt, float* __restrict__ stats1,
                       float* __restrict__ stats2, float* __restrict__ pooled,
                       uint* __restrict__ xwzero, int NN,
                       const int* __restrict__ ei, int* __restrict__ flags,
                       int* __restrict__ bcnt,
                       const float* __restrict__ W1, const float* __restrict__ W2,
                       ushort* __restrict__ wt1, ushort* __restrict__ wt2){
  int bid = blockIdx.x;
  if (bid < 512){
    int i = bid*256 + threadIdx.x;
    for (int t = i; t < NN; t += 512*256) cnt[t] = 0;
    if (i < 256){ stats1[i] = 0.f; stats2[i] = 0.f; }
    if (i < NGRAPH*HID) pooled[i] = 0.f;
    if (i < 64) xwzero[i] = 0u;   // zero row at index NN of xw
    if (i < 8)  bcnt[i] = 0;
    if (bid == 0 && threadIdx.x < 64){
      int t = threadIdx.x;
      bool nz = (ei[2*t + 1] != 0) || (ei[2*(t+64) + 1] != 0);
      unsigned long long m = __ballot(nz);
      if (t == 0) flags[1] = (m == 0ULL) ? 1 : 0;   // all-hi-words-zero => int64
    }
  } else {
    int b = bid - 512;                    // 8 blocks: 4 quarters x 2 matrices
    const float* W  = (b & 1) ? W2  : W1;
    ushort*      Wt = (b & 1) ? wt2 : wt1;
    int base = (b >> 1)*4096;
    for (int o = base + threadIdx.x; o < base + 4096; o += 256){
      int j    = o & 7;
      int lane = (o >> 3) & 63;
      int ct   = (o >> 9) & 7;
      int ks   = o >> 12;
      int k = ks*32 + (lane >> 4)*8 + j;
      int n = ct*16 + (lane & 15);
      Wt[o] = f2bf(W[(size_t)k*HID + n]);
    }
  }
}

__global__ void k_sentinel(ushort* out, int n){  // ws too small marker
  int i = blockIdx.x*blockDim.x + threadIdx.x;
  if (i < n) out[i] = 0x429A;
}

// ---------------- bucketing: edges -> 8 dst-partition pair lists ----------------
// two-phase per block: LDS-count chunk per part, reserve via 8 global atomics,
// re-scan and append (src,dst) int2. Pairs region p is read ONCE by hist/scatter.

#define BBLK 512

__global__ __launch_bounds__(256) void k_bucket(const int* __restrict__ ei,
    const int* __restrict__ flags, int2* __restrict__ pairs,
    int* __restrict__ bcnt, int E, int NN, int CAP){
  int is64 = flags[1];
  int per = (E + BBLK - 1)/BBLK;
  int e0 = blockIdx.x*per;
  int e1 = e0 + per; if (e1 > E) e1 = E;
  __shared__ int lcnt[8], lbase[8], lpos[8];
  if (threadIdx.x < 8){ lcnt[threadIdx.x] = 0; lpos[threadIdx.x] = 0; }
  __syncthreads();
  const int* dstp = ei + (is64 ? 2*(size_t)E : (size_t)E);
  for (int e = e0 + (int)threadIdx.x; e < e1; e += 256){
    int d = is64 ? dstp[2*(size_t)e] : dstp[e];
    int s = is64 ? ei[2*(size_t)e]   : ei[e];
    if ((uint)d < (uint)NN && (uint)s < (uint)NN){
      int part = (int)(((long long)d*8)/NN);
      atomicAdd(&lcnt[part], 1);
    }
  }
  __syncthreads();
  if (threadIdx.x < 8)
    lbase[threadIdx.x] = atomicAdd(&bcnt[threadIdx.x], lcnt[threadIdx.x]);
  __syncthreads();
  for (int e = e0 + (int)threadIdx.x; e < e1; e += 256){
    int d = is64 ? dstp[2*(size_t)e] : dstp[e];
    int s = is64 ? ei[2*(size_t)e]   : ei[e];
    if ((uint)d < (uint)NN && (uint)s < (uint)NN){
      int part = (int)(((long long)d*8)/NN);
      int slot = lbase[part] + atomicAdd(&lpos[part], 1);
      if (slot < CAP) pairs[(size_t)part*CAP + slot] = make_int2(s, d);
    }
  }
}

// ---------------- CSR build from buckets (part = blockIdx & 7, XCD-pinned) ----------------

#define HCH 64

__global__ __launch_bounds__(256) void k_hist(const int2* __restrict__ pairs,
    const int* __restrict__ bcnt, int* __restrict__ cnt, int CAP){
  int part  = blockIdx.x & 7;
  int chunk = blockIdx.x >> 3;
  int n = bcnt[part]; if (n > CAP) n = CAP;
  int per = (n + HCH - 1)/HCH;
  int i0 = chunk*per, i1 = i0 + per; if (i1 > n) i1 = n;
  const int2* pp = pairs + (size_t)part*CAP;
  for (int i = i0 + (int)threadIdx.x; i < i1; i += 256)
    atomicAdd(&cnt[pp[i].y], 1);
}

__global__ __launch_bounds__(256) void k_scatter(const int2* __restrict__ pairs,
    const int* __restrict__ bcnt, int* __restrict__ cursor,
    int* __restrict__ srclist, int CAP){
  int part  = blockIdx.x & 7;
  int chunk = blockIdx.x >> 3;
  int n = bcnt[part]; if (n > CAP) n = CAP;
  int per = (n + HCH - 1)/HCH;
  int i0 = chunk*per, i1 = i0 + per; if (i1 > n) i1 = n;
  const int2* pp = pairs + (size_t)part*CAP;
  for (int i = i0 + (int)threadIdx.x; i < i1; i += 256){
    int2 pr = pp[i];
    srclist[atomicAdd(&cursor[pr.y], 1)] = pr.x;
  }
}

__global__ void k_scan1(const int* __restrict__ cnt, int* __restrict__ partials,
                        float* __restrict__ dinv, int NN){
  int t = threadIdx.x;
  int base = blockIdx.x*1024 + t*4;
  int v0=0,v1=0,v2=0,v3=0;
  if (base + 3 < NN){ int4 v = *(const int4*)(cnt + base); v0=v.x; v1=v.y; v2=v.z; v3=v.w; }
  else {
    if (base+0 < NN) v0 = cnt[base+0];
    if (base+1 < NN) v1 = cnt[base+1];
    if (base+2 < NN) v2 = cnt[base+2];
    if (base+3 < NN) v3 = cnt[base+3];
  }
  if (base+0 < NN) dinv[base+0] = rsqrtf((float)(v0+1));
  if (base+1 < NN) dinv[base+1] = rsqrtf((float)(v1+1));
  if (base+2 < NN) dinv[base+2] = rsqrtf((float)(v2+1));
  if (base+3 < NN) dinv[base+3] = rsqrtf((float)(v3+1));
  __shared__ int red[256];
  red[t] = v0+v1+v2+v3;
  __syncthreads();
  for (int off=128; off>0; off>>=1){
    if (t < off) red[t] += red[t+off];
    __syncthreads();
  }
  if (t==0) partials[blockIdx.x] = red[0];
}

// scan3 computes its own partial-prefix; writes offs AND cursor copy.
__global__ void k_scan3(const int* __restrict__ cnt, const int* __restrict__ partials,
                        int* __restrict__ offs, int* __restrict__ cursor, int NN){
  int t = threadIdx.x;
  __shared__ int red2[256];
  int lp = 0;
  for (int i = t; i < (int)blockIdx.x; i += 256) lp += partials[i];
  red2[t] = lp;
  __syncthreads();
  for (int off=128; off>0; off>>=1){
    if (t < off) red2[t] += red2[t+off];
    __syncthreads();
  }
  int pbase = red2[0];
  if (t == 0 && blockIdx.x == gridDim.x-1)
    offs[NN] = pbase + partials[blockIdx.x];
  __syncthreads();

  int base = blockIdx.x*1024 + t*4;
  int v0=0,v1=0,v2=0,v3=0;
  if (base + 3 < NN){ int4 v = *(const int4*)(cnt + base); v0=v.x; v1=v.y; v2=v.z; v3=v.w; }
  else {
    if (base+0 < NN) v0 = cnt[base+0];
    if (base+1 < NN) v1 = cnt[base+1];
    if (base+2 < NN) v2 = cnt[base+2];
    if (base+3 < NN) v3 = cnt[base+3];
  }
  int tsum = v0+v1+v2+v3;
  __shared__ int sc[256];
  sc[t] = tsum;
  __syncthreads();
  for (int off=1; off<256; off<<=1){
    int val = (t >= off) ? sc[t-off] : 0;
    __syncthreads();
    sc[t] += val;
    __syncthreads();
  }
  int run = pbase + sc[t] - tsum;
  if (base+0 < NN){ offs[base+0] = run; cursor[base+0] = run; run += v0; }
  if (base+1 < NN){ offs[base+1] = run; cursor[base+1] = run; run += v1; }
  if (base+2 < NN){ offs[base+2] = run; cursor[base+2] = run; run += v2; }
  if (base+3 < NN){ offs[base+3] = run; cursor[base+3] = run; run += v3; }
}

// ---------------- GEMM1: f32 x [N,128] @ Wt(bf16,frag) -> xws bf16 (scaled by dinv) ----------------

__global__ __launch_bounds__(256) void k_gemm1(const float* __restrict__ A,
    const ushort* __restrict__ Wt, const float* __restrict__ dinv,
    ushort* __restrict__ O, int NN){
  __shared__ ushort wlds[16384];
  int tid = threadIdx.x;
  {
    const uint4* s = (const uint4*)Wt;
    uint4* d = (uint4*)wlds;
    #pragma unroll
    for (int i = 0; i < 8; i++) d[tid + i*256] = s[tid + i*256];
  }
  __syncthreads();
  int wave = tid >> 6, lane = tid & 63, m = lane & 15, q = lane >> 4;
  int rowbase = blockIdx.x*64 + wave*16;
  int ar = rowbase + m; if (ar >= NN) ar = NN-1;
  const float* arow = A + (size_t)ar*HID;
  short8 af[4];
  #pragma unroll
  for (int ks=0; ks<4; ks++){
    int kb = ks*32 + q*8;
    float4 f0 = *(const float4*)(arow + kb);
    float4 f1 = *(const float4*)(arow + kb + 4);
    short8 t;
    t[0]=(short)f2bf(nanz(f0.x)); t[1]=(short)f2bf(nanz(f0.y));
    t[2]=(short)f2bf(nanz(f0.z)); t[3]=(short)f2bf(nanz(f0.w));
    t[4]=(short)f2bf(nanz(f1.x)); t[5]=(short)f2bf(nanz(f1.y));
    t[6]=(short)f2bf(nanz(f1.z)); t[7]=(short)f2bf(nanz(f1.w));
    af[ks] = t;
  }
  floatx4 acc[8];
  #pragma unroll
  for (int ct=0; ct<8; ct++) acc[ct] = (floatx4){0.f,0.f,0.f,0.f};
  #pragma unroll
  for (int ks=0; ks<4; ks++){
    #pragma unroll
    for (int ct=0; ct<8; ct++){
      short8 bfrag = *(const short8*)&wlds[(((ks*8+ct)*64) + lane)*8];
      acc[ct] = __builtin_amdgcn_mfma_f32_16x16x32_bf16(af[ks], bfrag, acc[ct], 0, 0, 0);
    }
  }
  float dv[4];
  #pragma unroll
  for (int i=0;i<4;i++){ int r = rowbase + q*4 + i; dv[i] = (r < NN) ? dinv[r] : 0.f; }
  #pragma unroll
  for (int ct=0; ct<8; ct++){
    #pragma unroll
    for (int i=0;i<4;i++){
      int r = rowbase + q*4 + i;
      if (r < NN) O[(size_t)r*HID + ct*16 + m] = f2bf(acc[ct][i]*dv[i]);
    }
  }
}

// ---------------- GEMM2: BN+ReLU(agg) @ Wt2 -> xws bf16; BN coef computed in preamble ----------------

__global__ __launch_bounds__(256) void k_gemm2(const uint* __restrict__ agg,
    const float* __restrict__ stats, const float* __restrict__ gam,
    const float* __restrict__ bet, const ushort* __restrict__ Wt,
    const float* __restrict__ dinv, ushort* __restrict__ O, int NN, float invn){
  __shared__ ushort wlds[16384];
  __shared__ float cA[128], cB[128];
  int tid = threadIdx.x;
  {
    const uint4* s = (const uint4*)Wt;
    uint4* d = (uint4*)wlds;
    #pragma unroll
    for (int i = 0; i < 8; i++) d[tid + i*256] = s[tid + i*256];
    if (tid < 128){
      float sm = stats[tid], sq = stats[128+tid];
      float mean = sm*invn;
      float var = fmaxf(sq*invn - mean*mean, 0.f);
      float a = gam[tid] * rsqrtf(var + 1e-5f);
      cA[tid] = a;
      cB[tid] = bet[tid] - mean*a;
    }
  }
  __syncthreads();
  int wave = tid >> 6, lane = tid & 63, m = lane & 15, q = lane >> 4;
  int rowbase = blockIdx.x*64 + wave*16;
  int ar = rowbase + m; if (ar >= NN) ar = NN-1;
  const uint* arow = agg + (size_t)ar*64;
  short8 af[4];
  #pragma unroll
  for (int ks=0; ks<4; ks++){
    int kb = ks*32 + q*8;
    uint4 u = *(const uint4*)(arow + (kb >> 1));
    short8 t;
    uint uw[4] = {u.x, u.y, u.z, u.w};
    #pragma unroll
    for (int p=0; p<4; p++){
      int k0 = kb + 2*p;
      float v0 = fmaxf(cA[k0]  *bflo(uw[p]) + cB[k0],   0.f);
      float v1 = fmaxf(cA[k0+1]*bfhi(uw[p]) + cB[k0+1], 0.f);
      t[2*p]   = (short)f2bf(v0);
      t[2*p+1] = (short)f2bf(v1);
    }
    af[ks] = t;
  }
  floatx4 acc[8];
  #pragma unroll
  for (int ct=0; ct<8; ct++) acc[ct] = (floatx4){0.f,0.f,0.f,0.f};
  #pragma unroll
  for (int ks=0; ks<4; ks++){
    #pragma unroll
    for (int ct=0; ct<8; ct++){
      short8 bfrag = *(const short8*)&wlds[(((ks*8+ct)*64) + lane)*8];
      acc[ct] = __builtin_amdgcn_mfma_f32_16x16x32_bf16(af[ks], bfrag, acc[ct], 0, 0, 0);
    }
  }
  float dv[4];
  #pragma unroll
  for (int i=0;i<4;i++){ int r = rowbase + q*4 + i; dv[i] = (r < NN) ? dinv[r] : 0.f; }
  #pragma unroll
  for (int ct=0; ct<8; ct++){
    #pragma unroll
    for (int i=0;i<4;i++){
      int r = rowbase + q*4 + i;
      if (r < NN) O[(size_t)r*HID + ct*16 + m] = f2bf(acc[ct][i]*dv[i]);
    }
  }
}

// ---------------- aggregation: full-row scalar 4B gathers, 8 in flight, zero-row pad ----------------

__global__ __launch_bounds__(256) void k_agg(const uint* __restrict__ xw,
    const int* __restrict__ offs, const int* __restrict__ srclist,
    const float* __restrict__ dinv, uint* __restrict__ agg,
    float* __restrict__ stats, int NN){
  __shared__ float lstat[256];
  lstat[threadIdx.x] = 0.f;
  __syncthreads();
  int wib = threadIdx.x >> 6;
  int lane = threadIdx.x & 63;
  int wid = blockIdx.x*4 + wib;
  int nw = gridDim.x*4;
  float s0=0.f, s1=0.f, q0=0.f, q1=0.f;
  for (int n = wid; n < NN; n += nw){
    int lo = offs[n], hi = offs[n+1];
    float dvn = dinv[n];
    float a0 = 0.f, a1 = 0.f;
    for (int base = lo; base < hi; base += 64){
      int c = hi - base; if (c > 64) c = 64;
      int sidx = (lane < c) ? srclist[base + lane] : NN;   // NN = zero row
      for (int jb = 0; jb < c; jb += 8){
        uint w[8];
        #pragma unroll
        for (int t = 0; t < 8; t++){
          int sj = __shfl(sidx, jb + t, 64);
          w[t] = xw[(size_t)sj*64 + lane];
        }
        #pragma unroll
        for (int t = 0; t < 8; t++){
          a0 += bflo(w[t]);
          a1 += bfhi(w[t]);
        }
      }
    }
    uint wsf = xw[(size_t)n*64 + lane];     // self loop
    a0 = (a0 + bflo(wsf)) * dvn;
    a1 = (a1 + bfhi(wsf)) * dvn;
    agg[(size_t)n*64 + lane] = pack2(a0, a1);
    s0 += a0; s1 += a1; q0 += a0*a0; q1 += a1*a1;
  }
  int ch = lane*2;
  atomicAdd(&lstat[ch],       s0);
  atomicAdd(&lstat[ch+1],     s1);
  atomicAdd(&lstat[128+ch],   q0);
  atomicAdd(&lstat[128+ch+1], q1);
  __syncthreads();
  atomicAdd(&stats[threadIdx.x], lstat[threadIdx.x]);
}

// ---------------- pool: BN coef from stats in preamble, BN+ReLU fused, split grid ----------------

#define PSPLIT 16

__global__ __launch_bounds__(256) void k_pool(const uint* __restrict__ agg32,
    const int* __restrict__ batch, const float* __restrict__ stats,
    const float* __restrict__ gam, const float* __restrict__ bet,
    float* __restrict__ pooled, int* __restrict__ counts,
    int NN, const int* __restrict__ flags, float invn){
  int is64 = flags[1];
  __shared__ int bounds[2];
  __shared__ float cA[128], cB[128];
  int g  = blockIdx.x;
  int si = blockIdx.y;
  int tid = threadIdx.x;
  if (tid < 128){
    float sm = stats[tid], sq = stats[128+tid];
    float mean = sm*invn;
    float var = fmaxf(sq*invn - mean*mean, 0.f);
    float a = gam[tid] * rsqrtf(var + 1e-5f);
    cA[tid] = a;
    cB[tid] = bet[tid] - mean*a;
  }
  if (tid == 0){
    int lo=0, hi=NN;
    while (lo<hi){ int mid=(lo+hi)>>1; if (bat(batch,mid,is64) < g) lo=mid+1; else hi=mid; }
    bounds[0] = lo;
    int lo2=lo, hi2=NN;
    while (lo2<hi2){ int mid=(lo2+hi2)>>1; if (bat(batch,mid,is64) < g+1) lo2=mid+1; else hi2=mid; }
    bounds[1] = lo2;
    if (si == 0) counts[g] = hi2 - lo;
  }
  __syncthreads();
  int lo = bounds[0], hi = bounds[1];
  int cnt = hi - lo;
  int chunk = (cnt + PSPLIT - 1) / PSPLIT;
  int s = lo + si*chunk;
  int e = s + chunk; if (e > hi) e = hi;
  int lane = tid & 63, rg = tid >> 6;
  int ch = lane*2;
  float a0c = cA[ch],   b0c = cB[ch];
  float a1c = cA[ch+1], b1c = cB[ch+1];
  float acc0 = 0.f, acc1 = 0.f;
  for (int r = s + rg; r < e; r += 4){
    uint w = agg32[(size_t)r*64 + lane];
    acc0 += fmaxf(a0c*bflo(w) + b0c, 0.f);
    acc1 += fmaxf(a1c*bfhi(w) + b1c, 0.f);
  }
  __shared__ float red[512];
  red[tid] = acc0;
  red[256+tid] = acc1;
  __syncthreads();
  if (tid < 64){
    float s0 = red[tid] + red[tid+64] + red[tid+128] + red[tid+192];
    float s1 = red[256+tid] + red[320+tid] + red[384+tid] + red[448+tid];
    atomicAdd(&pooled[g*HID + ch],     s0);
    atomicAdd(&pooled[g*HID + ch + 1], s1);
  }
}

// ---------------- classifier MLP (tiny), f32; divides pooled sums by counts ----------------

__global__ void k_mlp(const float* __restrict__ pooled, const int* __restrict__ counts,
                      const float* __restrict__ Wc1, const float* __restrict__ bc1,
                      const float* __restrict__ Wc2, const float* __restrict__ bc2,
                      float* __restrict__ out){
  __shared__ float P[NGRAPH*HID];
  __shared__ float Z[NGRAPH*64];
  int tid = threadIdx.x; // 256
  for (int i = tid; i < NGRAPH*HID; i += 256){
    int g = i >> 7;
    float c = (float)counts[g];
    P[i] = pooled[i] / fmaxf(c, 1.f);
  }
  __syncthreads();
  for (int idx = tid; idx < NGRAPH*64; idx += 256){
    int g = idx >> 6, j = idx & 63;
    float acc = bc1[j];
    for (int k = 0; k < HID; k++) acc += P[g*HID + k] * Wc1[k*64 + j];
    Z[idx] = fmaxf(acc, 0.f);
  }
  __syncthreads();
  if (tid < NGRAPH*2){
    int g = tid >> 1, o = tid & 1;
    float acc = bc2[o];
    for (int k = 0; k < 64; k++) acc += Z[g*64 + k] * Wc2[k*2 + o];
    out[tid] = nanz(acc);
  }
}

extern "C" void kernel_launch(void* const* d_in, const int* in_sizes, int n_in,
                              void* d_out, int out_size, void* d_ws, size_t ws_size,
                              hipStream_t stream){
  const float* x   = (const float*)d_in[0];
  const int*   ei  = (const int*)d_in[1];
  const int* batch = (const int*)d_in[2];
  const float* W1  = (const float*)d_in[3];
  // d_in[4] = b1: cancels through BN
  const float* g1  = (const float*)d_in[5];
  const float* be1 = (const float*)d_in[6];
  const float* W2  = (const float*)d_in[7];
  // d_in[8] = b2: cancels through BN
  const float* g2  = (const float*)d_in[9];
  const float* be2 = (const float*)d_in[10];
  const float* Wc1 = (const float*)d_in[11];
  const float* bc1 = (const float*)d_in[12];
  const float* Wc2 = (const float*)d_in[13];
  const float* bc2 = (const float*)d_in[14];

  const int NN = in_sizes[2];        // 100000 nodes
  const int E  = in_sizes[1] / 2;    // 1.6M edges
  const int CAP = E/8 + 32768;       // per-part bucket capacity (78 sigma margin)

  char* p = (char*)d_ws;
  auto carve = [&](size_t bytes)->char*{
    char* r = p; p += (bytes + 255) & ~(size_t)255; return r;
  };
  int NPART = (NN + 1023)/1024;
  int*   flags    = (int*)  carve(64*4);
  int*   bcnt     = (int*)  carve(64*4);
  int*   cnt      = (int*)  carve((size_t)NN*4);
  int*   cursor   = (int*)  carve(((size_t)NN+1)*4);
  int*   offs     = (int*)  carve(((size_t)NN+1)*4);
  int*   partials = (int*)  carve((size_t)NPART*4);
  int*   srclist  = (int*)  carve((size_t)E*4);
  int2*  pairs    = (int2*) carve((size_t)8*CAP*8);
  float* dinv     = (float*)carve((size_t)NN*4);
  float* stats1   = (float*)carve(256*4);
  float* stats2   = (float*)carve(256*4);
  float* pooled   = (float*)carve((size_t)NGRAPH*HID*4);
  int*   counts   = (int*)  carve(NGRAPH*4);
  ushort* wt1     = (ushort*)carve(16384*2);
  ushort* wt2     = (ushort*)carve(16384*2);
  ushort* xw      = (ushort*)carve(((size_t)NN+1)*HID*2);  // +1 zero row
  ushort* agg     = (ushort*)carve((size_t)NN*HID*2);
  if ((size_t)(p - (char*)d_ws) > ws_size){
    k_sentinel<<<(out_size+255)/256, 256, 0, stream>>>((ushort*)d_out, out_size);
    return;
  }

  const float invn = 1.f/(float)NN;

  k_prep   <<<520, 256, 0, stream>>>(cnt, stats1, stats2, pooled,
                                     (uint*)(xw + (size_t)NN*HID), NN, ei, flags,
                                     bcnt, W1, W2, wt1, wt2);
  k_bucket <<<BBLK, 256, 0, stream>>>(ei, flags, pairs, bcnt, E, NN, CAP);

  k_hist   <<<8*HCH, 256, 0, stream>>>(pairs, bcnt, cnt, CAP);
  k_scan1  <<<NPART, 256, 0, stream>>>(cnt, partials, dinv, NN);
  k_scan3  <<<NPART, 256, 0, stream>>>(cnt, partials, offs, cursor, NN);
  k_scatter<<<8*HCH, 256, 0, stream>>>(pairs, bcnt, cursor, srclist, CAP);

  int gblocks = (NN + 63)/64;
  // layer 1
  k_gemm1<<<gblocks, 256, 0, stream>>>(x, wt1, dinv, xw, NN);
  k_agg  <<<2048, 256, 0, stream>>>((const uint*)xw, offs, srclist, dinv, (uint*)agg, stats1, NN);
  // layer 2 (BN coef computed per-block from stats1; BN+ReLU fused into A-load)
  k_gemm2<<<gblocks, 256, 0, stream>>>((const uint*)agg, stats1, g1, be1, wt2, dinv, xw, NN, invn);
  k_agg  <<<2048, 256, 0, stream>>>((const uint*)xw, offs, srclist, dinv, (uint*)agg, stats2, NN);
  // pool (BN coef from stats2, BN+ReLU fused, split grid) + classifier
  k_pool <<<dim3(NGRAPH, PSPLIT), 256, 0, stream>>>((const uint*)agg, batch, stats2, g2, be2,
                                                    pooled, counts, NN, flags, invn);
  k_mlp  <<<1, 256, 0, stream>>>(pooled, counts, Wc1, bc1, Wc2, bc2, (float*)d_out);
}

// Round 11
// 526.506 us; speedup vs baseline: 1.0728x; 1.0728x over previous
//
#include <hip/hip_runtime.h>

typedef unsigned int uint;
typedef unsigned short ushort;

#define HID 128
#define NGRAPH 64

typedef __attribute__((ext_vector_type(8))) short short8;
typedef __attribute__((ext_vector_type(4))) float floatx4;

__device__ __forceinline__ float bflo(uint w){ return __uint_as_float(w<<16); }
__device__ __forceinline__ float bfhi(uint w){ return __uint_as_float(w & 0xffff0000u); }
__device__ __forceinline__ float bf2f(ushort u){ return __uint_as_float(((uint)u)<<16); }
__device__ __forceinline__ ushort f2bf(float f){
  uint u = __float_as_uint(f);
  u = u + 0x7fffu + ((u>>16)&1u);
  return (ushort)(u>>16);
}
__device__ __forceinline__ uint pack2(float a, float b){
  return (uint)f2bf(a) | ((uint)f2bf(b)<<16);
}
__device__ __forceinline__ float nanz(float v){ return (v==v) ? v : 0.f; }

__device__ __forceinline__ int bat(const int* b, int i, int is64){
  return is64 ? b[2*(size_t)i] : b[i];
}

// ---------------- prep: zero + detect + W repack ----------------
// blocks 0..511 : zero cnt/stats/pooled/xw-zero-row; block 0 writes flags[1]
// blocks 512..519: repack W1/W2 into bf16 MFMA-B-fragment layout
__global__ void k_prep(int* __restrict__ cnt, float* __restrict__ stats1,
                       float* __restrict__ stats2, float* __restrict__ pooled,
                       uint* __restrict__ xwzero, int NN,
                       const int* __restrict__ ei, int* __restrict__ flags,
                       const float* __restrict__ W1, const float* __restrict__ W2,
                       ushort* __restrict__ wt1, ushort* __restrict__ wt2){
  int bid = blockIdx.x;
  if (bid < 512){
    int i = bid*256 + threadIdx.x;
    for (int t = i; t < NN; t += 512*256) cnt[t] = 0;
    if (i < 256){ stats1[i] = 0.f; stats2[i] = 0.f; }
    if (i < NGRAPH*HID) pooled[i] = 0.f;
    if (i < 64) xwzero[i] = 0u;   // zero row at index NN of xw
    if (bid == 0 && threadIdx.x < 64){
      int t = threadIdx.x;
      bool nz = (ei[2*t + 1] != 0) || (ei[2*(t+64) + 1] != 0);
      unsigned long long m = __ballot(nz);
      if (t == 0) flags[1] = (m == 0ULL) ? 1 : 0;   // all-hi-words-zero => int64
    }
  } else {
    int b = bid - 512;                    // 8 blocks: 4 quarters x 2 matrices
    const float* W  = (b & 1) ? W2  : W1;
    ushort*      Wt = (b & 1) ? wt2 : wt1;
    int base = (b >> 1)*4096;
    for (int o = base + threadIdx.x; o < base + 4096; o += 256){
      int j    = o & 7;
      int lane = (o >> 3) & 63;
      int ct   = (o >> 9) & 7;
      int ks   = o >> 12;
      int k = ks*32 + (lane >> 4)*8 + j;
      int n = ct*16 + (lane & 15);
      Wt[o] = f2bf(W[(size_t)k*HID + n]);
    }
  }
}

__global__ void k_sentinel(ushort* out, int n){  // ws too small marker
  int i = blockIdx.x*blockDim.x + threadIdx.x;
  if (i < n) out[i] = 0x429A;
}

// ---------------- compact + fused histogram (reads edge list exactly once) ----------------
__global__ __launch_bounds__(256) void k_compacthist(const int* __restrict__ ei,
    const int* __restrict__ flags, int* __restrict__ src32, int* __restrict__ dst32,
    int* __restrict__ cnt, int E, int NN){
  int is64 = flags[1];
  int i = blockIdx.x*256 + (int)threadIdx.x;
  int stride = gridDim.x*256;
  if (is64){
    for (int e = i; e < E; e += stride){
      int s = ei[2*(size_t)e];
      int d = ei[2*((size_t)E + e)];
      src32[e] = s; dst32[e] = d;
      if ((uint)d < (uint)NN && (uint)s < (uint)NN) atomicAdd(&cnt[d], 1);
    }
  } else {
    for (int e = i; e < E; e += stride){
      int s = ei[e];
      int d = ei[(size_t)E + e];
      src32[e] = s; dst32[e] = d;
      if ((uint)d < (uint)NN && (uint)s < (uint)NN) atomicAdd(&cnt[d], 1);
    }
  }
}

__global__ void k_scan1(const int* __restrict__ cnt, int* __restrict__ partials,
                        float* __restrict__ dinv, int NN){
  int t = threadIdx.x;
  int base = blockIdx.x*1024 + t*4;
  int v0=0,v1=0,v2=0,v3=0;
  if (base + 3 < NN){ int4 v = *(const int4*)(cnt + base); v0=v.x; v1=v.y; v2=v.z; v3=v.w; }
  else {
    if (base+0 < NN) v0 = cnt[base+0];
    if (base+1 < NN) v1 = cnt[base+1];
    if (base+2 < NN) v2 = cnt[base+2];
    if (base+3 < NN) v3 = cnt[base+3];
  }
  if (base+0 < NN) dinv[base+0] = rsqrtf((float)(v0+1));
  if (base+1 < NN) dinv[base+1] = rsqrtf((float)(v1+1));
  if (base+2 < NN) dinv[base+2] = rsqrtf((float)(v2+1));
  if (base+3 < NN) dinv[base+3] = rsqrtf((float)(v3+1));
  __shared__ int red[256];
  red[t] = v0+v1+v2+v3;
  __syncthreads();
  for (int off=128; off>0; off>>=1){
    if (t < off) red[t] += red[t+off];
    __syncthreads();
  }
  if (t==0) partials[blockIdx.x] = red[0];
}

// scan3 computes its own partial-prefix; writes offs AND cursor copy.
__global__ void k_scan3(const int* __restrict__ cnt, const int* __restrict__ partials,
                        int* __restrict__ offs, int* __restrict__ cursor, int NN){
  int t = threadIdx.x;
  __shared__ int red2[256];
  int lp = 0;
  for (int i = t; i < (int)blockIdx.x; i += 256) lp += partials[i];
  red2[t] = lp;
  __syncthreads();
  for (int off=128; off>0; off>>=1){
    if (t < off) red2[t] += red2[t+off];
    __syncthreads();
  }
  int pbase = red2[0];
  if (t == 0 && blockIdx.x == gridDim.x-1)
    offs[NN] = pbase + partials[blockIdx.x];
  __syncthreads();

  int base = blockIdx.x*1024 + t*4;
  int v0=0,v1=0,v2=0,v3=0;
  if (base + 3 < NN){ int4 v = *(const int4*)(cnt + base); v0=v.x; v1=v.y; v2=v.z; v3=v.w; }
  else {
    if (base+0 < NN) v0 = cnt[base+0];
    if (base+1 < NN) v1 = cnt[base+1];
    if (base+2 < NN) v2 = cnt[base+2];
    if (base+3 < NN) v3 = cnt[base+3];
  }
  int tsum = v0+v1+v2+v3;
  __shared__ int sc[256];
  sc[t] = tsum;
  __syncthreads();
  for (int off=1; off<256; off<<=1){
    int val = (t >= off) ? sc[t-off] : 0;
    __syncthreads();
    sc[t] += val;
    __syncthreads();
  }
  int run = pbase + sc[t] - tsum;
  if (base+0 < NN){ offs[base+0] = run; cursor[base+0] = run; run += v0; }
  if (base+1 < NN){ offs[base+1] = run; cursor[base+1] = run; run += v1; }
  if (base+2 < NN){ offs[base+2] = run; cursor[base+2] = run; run += v2; }
  if (base+3 < NN){ offs[base+3] = run; cursor[base+3] = run; run += v3; }
}

// ---------------- scatter: XCD dst-partitioned (part = blockIdx & 7) ----------------

#define NCHUNK 256

__global__ __launch_bounds__(256) void k_scatter(const int* __restrict__ src32,
    const int* __restrict__ dst32, int* __restrict__ cursor,
    int* __restrict__ srclist, int E, int NN){
  int part  = blockIdx.x & 7;
  int chunk = blockIdx.x >> 3;
  int p0 = (int)(((long long)NN *  part   ) >> 3);
  int p1 = (int)(((long long)NN * (part+1)) >> 3);
  int per = (E + NCHUNK - 1) / NCHUNK;
  int e0 = chunk * per;
  int e1 = e0 + per; if (e1 > E) e1 = E;
  for (int e = e0 + (int)threadIdx.x; e < e1; e += 256){
    int d = dst32[e];
    if (d >= p0 && d < p1){
      int s = src32[e];
      if ((uint)s < (uint)NN)
        srclist[atomicAdd(&cursor[d], 1)] = s;
    }
  }
}

// ---------------- GEMM1: f32 x [N,128] @ Wt(bf16,frag) -> xws bf16 (scaled by dinv) ----------------

__global__ __launch_bounds__(256) void k_gemm1(const float* __restrict__ A,
    const ushort* __restrict__ Wt, const float* __restrict__ dinv,
    ushort* __restrict__ O, int NN){
  __shared__ ushort wlds[16384];
  int tid = threadIdx.x;
  {
    const uint4* s = (const uint4*)Wt;
    uint4* d = (uint4*)wlds;
    #pragma unroll
    for (int i = 0; i < 8; i++) d[tid + i*256] = s[tid + i*256];
  }
  __syncthreads();
  int wave = tid >> 6, lane = tid & 63, m = lane & 15, q = lane >> 4;
  int rowbase = blockIdx.x*64 + wave*16;
  int ar = rowbase + m; if (ar >= NN) ar = NN-1;
  const float* arow = A + (size_t)ar*HID;
  short8 af[4];
  #pragma unroll
  for (int ks=0; ks<4; ks++){
    int kb = ks*32 + q*8;
    float4 f0 = *(const float4*)(arow + kb);
    float4 f1 = *(const float4*)(arow + kb + 4);
    short8 t;
    t[0]=(short)f2bf(nanz(f0.x)); t[1]=(short)f2bf(nanz(f0.y));
    t[2]=(short)f2bf(nanz(f0.z)); t[3]=(short)f2bf(nanz(f0.w));
    t[4]=(short)f2bf(nanz(f1.x)); t[5]=(short)f2bf(nanz(f1.y));
    t[6]=(short)f2bf(nanz(f1.z)); t[7]=(short)f2bf(nanz(f1.w));
    af[ks] = t;
  }
  floatx4 acc[8];
  #pragma unroll
  for (int ct=0; ct<8; ct++) acc[ct] = (floatx4){0.f,0.f,0.f,0.f};
  #pragma unroll
  for (int ks=0; ks<4; ks++){
    #pragma unroll
    for (int ct=0; ct<8; ct++){
      short8 bfrag = *(const short8*)&wlds[(((ks*8+ct)*64) + lane)*8];
      acc[ct] = __builtin_amdgcn_mfma_f32_16x16x32_bf16(af[ks], bfrag, acc[ct], 0, 0, 0);
    }
  }
  float dv[4];
  #pragma unroll
  for (int i=0;i<4;i++){ int r = rowbase + q*4 + i; dv[i] = (r < NN) ? dinv[r] : 0.f; }
  #pragma unroll
  for (int ct=0; ct<8; ct++){
    #pragma unroll
    for (int i=0;i<4;i++){
      int r = rowbase + q*4 + i;
      if (r < NN) O[(size_t)r*HID + ct*16 + m] = f2bf(acc[ct][i]*dv[i]);
    }
  }
}

// ---------------- GEMM2: BN+ReLU(agg) @ Wt2 -> xws bf16; BN coef computed in preamble ----------------

__global__ __launch_bounds__(256) void k_gemm2(const uint* __restrict__ agg,
    const float* __restrict__ stats, const float* __restrict__ gam,
    const float* __restrict__ bet, const ushort* __restrict__ Wt,
    const float* __restrict__ dinv, ushort* __restrict__ O, int NN, float invn){
  __shared__ ushort wlds[16384];
  __shared__ float cA[128], cB[128];
  int tid = threadIdx.x;
  {
    const uint4* s = (const uint4*)Wt;
    uint4* d = (uint4*)wlds;
    #pragma unroll
    for (int i = 0; i < 8; i++) d[tid + i*256] = s[tid + i*256];
    if (tid < 128){
      float sm = stats[tid], sq = stats[128+tid];
      float mean = sm*invn;
      float var = fmaxf(sq*invn - mean*mean, 0.f);
      float a = gam[tid] * rsqrtf(var + 1e-5f);
      cA[tid] = a;
      cB[tid] = bet[tid] - mean*a;
    }
  }
  __syncthreads();
  int wave = tid >> 6, lane = tid & 63, m = lane & 15, q = lane >> 4;
  int rowbase = blockIdx.x*64 + wave*16;
  int ar = rowbase + m; if (ar >= NN) ar = NN-1;
  const uint* arow = agg + (size_t)ar*64;
  short8 af[4];
  #pragma unroll
  for (int ks=0; ks<4; ks++){
    int kb = ks*32 + q*8;
    uint4 u = *(const uint4*)(arow + (kb >> 1));
    short8 t;
    uint uw[4] = {u.x, u.y, u.z, u.w};
    #pragma unroll
    for (int p=0; p<4; p++){
      int k0 = kb + 2*p;
      float v0 = fmaxf(cA[k0]  *bflo(uw[p]) + cB[k0],   0.f);
      float v1 = fmaxf(cA[k0+1]*bfhi(uw[p]) + cB[k0+1], 0.f);
      t[2*p]   = (short)f2bf(v0);
      t[2*p+1] = (short)f2bf(v1);
    }
    af[ks] = t;
  }
  floatx4 acc[8];
  #pragma unroll
  for (int ct=0; ct<8; ct++) acc[ct] = (floatx4){0.f,0.f,0.f,0.f};
  #pragma unroll
  for (int ks=0; ks<4; ks++){
    #pragma unroll
    for (int ct=0; ct<8; ct++){
      short8 bfrag = *(const short8*)&wlds[(((ks*8+ct)*64) + lane)*8];
      acc[ct] = __builtin_amdgcn_mfma_f32_16x16x32_bf16(af[ks], bfrag, acc[ct], 0, 0, 0);
    }
  }
  float dv[4];
  #pragma unroll
  for (int i=0;i<4;i++){ int r = rowbase + q*4 + i; dv[i] = (r < NN) ? dinv[r] : 0.f; }
  #pragma unroll
  for (int ct=0; ct<8; ct++){
    #pragma unroll
    for (int i=0;i<4;i++){
      int r = rowbase + q*4 + i;
      if (r < NN) O[(size_t)r*HID + ct*16 + m] = f2bf(acc[ct][i]*dv[i]);
    }
  }
}

// ---------------- aggregation: full-row scalar 4B gathers, 8 in flight, zero-row pad ----------------

__global__ __launch_bounds__(256) void k_agg(const uint* __restrict__ xw,
    const int* __restrict__ offs, const int* __restrict__ srclist,
    const float* __restrict__ dinv, uint* __restrict__ agg,
    float* __restrict__ stats, int NN){
  __shared__ float lstat[256];
  lstat[threadIdx.x] = 0.f;
  __syncthreads();
  int wib = threadIdx.x >> 6;
  int lane = threadIdx.x & 63;
  int wid = blockIdx.x*4 + wib;
  int nw = gridDim.x*4;
  float s0=0.f, s1=0.f, q0=0.f, q1=0.f;
  for (int n = wid; n < NN; n += nw){
    int lo = offs[n], hi = offs[n+1];
    float dvn = dinv[n];
    float a0 = 0.f, a1 = 0.f;
    for (int base = lo; base < hi; base += 64){
      int c = hi - base; if (c > 64) c = 64;
      int sidx = (lane < c) ? srclist[base + lane] : NN;   // NN = zero row
      for (int jb = 0; jb < c; jb += 8){
        uint w[8];
        #pragma unroll
        for (int t = 0; t < 8; t++){
          int sj = __shfl(sidx, jb + t, 64);
          w[t] = xw[(size_t)sj*64 + lane];
        }
        #pragma unroll
        for (int t = 0; t < 8; t++){
          a0 += bflo(w[t]);
          a1 += bfhi(w[t]);
        }
      }
    }
    uint wsf = xw[(size_t)n*64 + lane];     // self loop
    a0 = (a0 + bflo(wsf)) * dvn;
    a1 = (a1 + bfhi(wsf)) * dvn;
    agg[(size_t)n*64 + lane] = pack2(a0, a1);
    s0 += a0; s1 += a1; q0 += a0*a0; q1 += a1*a1;
  }
  int ch = lane*2;
  atomicAdd(&lstat[ch],       s0);
  atomicAdd(&lstat[ch+1],     s1);
  atomicAdd(&lstat[128+ch],   q0);
  atomicAdd(&lstat[128+ch+1], q1);
  __syncthreads();
  atomicAdd(&stats[threadIdx.x], lstat[threadIdx.x]);
}

// ---------------- pool: BN coef from stats in preamble, BN+ReLU fused, split grid ----------------

#define PSPLIT 16

__global__ __launch_bounds__(256) void k_pool(const uint* __restrict__ agg32,
    const int* __restrict__ batch, const float* __restrict__ stats,
    const float* __restrict__ gam, const float* __restrict__ bet,
    float* __restrict__ pooled, int* __restrict__ counts,
    int NN, const int* __restrict__ flags, float invn){
  int is64 = flags[1];
  __shared__ int bounds[2];
  __shared__ float cA[128], cB[128];
  int g  = blockIdx.x;
  int si = blockIdx.y;
  int tid = threadIdx.x;
  if (tid < 128){
    float sm = stats[tid], sq = stats[128+tid];
    float mean = sm*invn;
    float var = fmaxf(sq*invn - mean*mean, 0.f);
    float a = gam[tid] * rsqrtf(var + 1e-5f);
    cA[tid] = a;
    cB[tid] = bet[tid] - mean*a;
  }
  if (tid == 0){
    int lo=0, hi=NN;
    while (lo<hi){ int mid=(lo+hi)>>1; if (bat(batch,mid,is64) < g) lo=mid+1; else hi=mid; }
    bounds[0] = lo;
    int lo2=lo, hi2=NN;
    while (lo2<hi2){ int mid=(lo2+hi2)>>1; if (bat(batch,mid,is64) < g+1) lo2=mid+1; else hi2=mid; }
    bounds[1] = lo2;
    if (si == 0) counts[g] = hi2 - lo;
  }
  __syncthreads();
  int lo = bounds[0], hi = bounds[1];
  int cnt = hi - lo;
  int chunk = (cnt + PSPLIT - 1) / PSPLIT;
  int s = lo + si*chunk;
  int e = s + chunk; if (e > hi) e = hi;
  int lane = tid & 63, rg = tid >> 6;
  int ch = lane*2;
  float a0c = cA[ch],   b0c = cB[ch];
  float a1c = cA[ch+1], b1c = cB[ch+1];
  float acc0 = 0.f, acc1 = 0.f;
  for (int r = s + rg; r < e; r += 4){
    uint w = agg32[(size_t)r*64 + lane];
    acc0 += fmaxf(a0c*bflo(w) + b0c, 0.f);
    acc1 += fmaxf(a1c*bfhi(w) + b1c, 0.f);
  }
  __shared__ float red[512];
  red[tid] = acc0;
  red[256+tid] = acc1;
  __syncthreads();
  if (tid < 64){
    float s0 = red[tid] + red[tid+64] + red[tid+128] + red[tid+192];
    float s1 = red[256+tid] + red[320+tid] + red[384+tid] + red[448+tid];
    atomicAdd(&pooled[g*HID + ch],     s0);
    atomicAdd(&pooled[g*HID + ch + 1], s1);
  }
}

// ---------------- classifier MLP: one block per graph (parallel tail) ----------------

__global__ __launch_bounds__(128) void k_mlp(const float* __restrict__ pooled,
    const int* __restrict__ counts, const float* __restrict__ Wc1,
    const float* __restrict__ bc1, const float* __restrict__ Wc2,
    const float* __restrict__ bc2, float* __restrict__ out){
  int g = blockIdx.x;          // 64 blocks
  __shared__ float P[HID];
  __shared__ float Z[64];
  int tid = threadIdx.x;       // 128
  {
    float c = (float)counts[g];
    P[tid] = pooled[g*HID + tid] / fmaxf(c, 1.f);
  }
  __syncthreads();
  if (tid < 64){
    float acc = bc1[tid];
    for (int k = 0; k < HID; k++) acc += P[k] * Wc1[k*64 + tid];
    Z[tid] = fmaxf(acc, 0.f);
  }
  __syncthreads();
  if (tid < 2){
    float acc = bc2[tid];
    for (int k = 0; k < 64; k++) acc += Z[k] * Wc2[k*2 + tid];
    out[g*2 + tid] = nanz(acc);
  }
}

extern "C" void kernel_launch(void* const* d_in, const int* in_sizes, int n_in,
                              void* d_out, int out_size, void* d_ws, size_t ws_size,
                              hipStream_t stream){
  const float* x   = (const float*)d_in[0];
  const int*   ei  = (const int*)d_in[1];
  const int* batch = (const int*)d_in[2];
  const float* W1  = (const float*)d_in[3];
  // d_in[4] = b1: cancels through BN
  const float* g1  = (const float*)d_in[5];
  const float* be1 = (const float*)d_in[6];
  const float* W2  = (const float*)d_in[7];
  // d_in[8] = b2: cancels through BN
  const float* g2  = (const float*)d_in[9];
  const float* be2 = (const float*)d_in[10];
  const float* Wc1 = (const float*)d_in[11];
  const float* bc1 = (const float*)d_in[12];
  const float* Wc2 = (const float*)d_in[13];
  const float* bc2 = (const float*)d_in[14];

  const int NN = in_sizes[2];        // 100000 nodes
  const int E  = in_sizes[1] / 2;    // 1.6M edges

  char* p = (char*)d_ws;
  auto carve = [&](size_t bytes)->char*{
    char* r = p; p += (bytes + 255) & ~(size_t)255; return r;
  };
  int NPART = (NN + 1023)/1024;
  int*   flags    = (int*)  carve(64*4);
  int*   cnt      = (int*)  carve((size_t)NN*4);
  int*   cursor   = (int*)  carve(((size_t)NN+1)*4);
  int*   offs     = (int*)  carve(((size_t)NN+1)*4);
  int*   partials = (int*)  carve((size_t)NPART*4);
  int*   srclist  = (int*)  carve((size_t)E*4);
  int*   src32    = (int*)  carve((size_t)E*4);
  int*   dst32    = (int*)  carve((size_t)E*4);
  float* dinv     = (float*)carve((size_t)NN*4);
  float* stats1   = (float*)carve(256*4);
  float* stats2   = (float*)carve(256*4);
  float* pooled   = (float*)carve((size_t)NGRAPH*HID*4);
  int*   counts   = (int*)  carve(NGRAPH*4);
  ushort* wt1     = (ushort*)carve(16384*2);
  ushort* wt2     = (ushort*)carve(16384*2);
  ushort* xw      = (ushort*)carve(((size_t)NN+1)*HID*2);  // +1 zero row
  ushort* agg     = (ushort*)carve((size_t)NN*HID*2);
  if ((size_t)(p - (char*)d_ws) > ws_size){
    k_sentinel<<<(out_size+255)/256, 256, 0, stream>>>((ushort*)d_out, out_size);
    return;
  }

  const float invn = 1.f/(float)NN;

  k_prep       <<<520, 256, 0, stream>>>(cnt, stats1, stats2, pooled,
                                         (uint*)(xw + (size_t)NN*HID), NN, ei, flags,
                                         W1, W2, wt1, wt2);
  k_compacthist<<<512, 256, 0, stream>>>(ei, flags, src32, dst32, cnt, E, NN);
  k_scan1      <<<NPART, 256, 0, stream>>>(cnt, partials, dinv, NN);
  k_scan3      <<<NPART, 256, 0, stream>>>(cnt, partials, offs, cursor, NN);
  k_scatter    <<<NCHUNK*8, 256, 0, stream>>>(src32, dst32, cursor, srclist, E, NN);

  int gblocks = (NN + 63)/64;
  // layer 1
  k_gemm1<<<gblocks, 256, 0, stream>>>(x, wt1, dinv, xw, NN);
  k_agg  <<<2048, 256, 0, stream>>>((const uint*)xw, offs, srclist, dinv, (uint*)agg, stats1, NN);
  // layer 2 (BN coef computed per-block from stats1; BN+ReLU fused into A-load)
  k_gemm2<<<gblocks, 256, 0, stream>>>((const uint*)agg, stats1, g1, be1, wt2, dinv, xw, NN, invn);
  k_agg  <<<2048, 256, 0, stream>>>((const uint*)xw, offs, srclist, dinv, (uint*)agg, stats2, NN);
  // pool (BN coef from stats2, BN+ReLU fused, split grid) + classifier
  k_pool <<<dim3(NGRAPH, PSPLIT), 256, 0, stream>>>((const uint*)agg, batch, stats2, g2, be2,
                                                    pooled, counts, NN, flags, invn);
  k_mlp  <<<NGRAPH, 128, 0, stream>>>(pooled, counts, Wc1, bc1, Wc2, bc2, (float*)d_out);
}